// Round 1
// baseline (288.577 us; speedup 1.0000x reference)
//
#include <hip/hip_runtime.h>

typedef unsigned short ushort_t;
typedef unsigned int uint32;
typedef __attribute__((ext_vector_type(8))) short short8;
typedef __attribute__((ext_vector_type(4))) float float4v;
typedef __attribute__((ext_vector_type(4))) unsigned short ushort4v;

#define NEG_INF (-__builtin_inff())

__device__ __forceinline__ ushort_t f2bf(float f) {
  uint32 u = __float_as_uint(f);
  u += 0x7fffu + ((u >> 16) & 1u);
  return (ushort_t)(u >> 16);
}

__device__ __forceinline__ void glds16(const void* g, void* l) {
  __builtin_amdgcn_global_load_lds(
      (__attribute__((address_space(1))) const void*)g,
      (__attribute__((address_space(3))) void*)l, 16, 0, 0);
}

// ---------------- f32 -> bf16 conversion (vectorized) ----------------
__global__ __launch_bounds__(256) void cvt_f32_bf16_kernel(
    const float* __restrict__ in, ushort_t* __restrict__ out, int n4) {
  int i = blockIdx.x * 256 + threadIdx.x;
  if (i >= n4) return;
  float4v v = ((const float4v*)in)[i];
  ushort4v o;
  o.x = f2bf(v.x);
  o.y = f2bf(v.y);
  o.z = f2bf(v.z);
  o.w = f2bf(v.w);
  ((ushort4v*)out)[i] = o;
}

// ---------------- bf16 GEMM, C = A * B^T (both row-major, K contiguous) ----
// m97 structure: 128x128 tile, BK=32, 4 waves, each wave 64x64 (4x4 frags).
template <bool F32OUT>
__global__ __launch_bounds__(256) void gemm_bt128(
    const ushort_t* __restrict__ A, const ushort_t* __restrict__ B,
    void* __restrict__ Cout, int M, int N, int K) {
  __shared__ __align__(16) ushort_t Al[128][32];
  __shared__ __align__(16) ushort_t Bl[128][32];
  const int tid = threadIdx.x;
  const int w = tid >> 6, lane = tid & 63;
  const int l15 = lane & 15, lhi = lane >> 4;
  const int bm = blockIdx.y * 128, bn = blockIdx.x * 128;
  const int wm = (w >> 1) * 64, wn = (w & 1) * 64;

  float4v zero4 = {0.f, 0.f, 0.f, 0.f};
  float4v acc[4][4];
  for (int i = 0; i < 4; i++)
    for (int j = 0; j < 4; j++) acc[i][j] = zero4;

  const int r = tid >> 2;        // 0..63 staging row
  const int cc = (tid & 3) * 8;  // staging col chunk (8 bf16 = 16B)
  const ushort_t* ga = A + (size_t)(bm + r) * K + cc;
  const ushort_t* gb = B + (size_t)(bn + r) * K + cc;
  char* lA = (char*)&Al[0][0];
  char* lB = (char*)&Bl[0][0];
  const int wb = w * 1024;  // wave-uniform LDS byte base (lane*16 added by HW)

  for (int kt = 0; kt < K; kt += 32) {
    glds16(ga + kt, lA + wb);
    glds16(ga + (size_t)64 * K + kt, lA + 4096 + wb);
    glds16(gb + kt, lB + wb);
    glds16(gb + (size_t)64 * K + kt, lB + 4096 + wb);
    __syncthreads();  // drains vmcnt (global_load_lds) before reads
    short8 af[4], bfr[4];
#pragma unroll
    for (int mi = 0; mi < 4; mi++)
      af[mi] = *(const short8*)&Al[wm + mi * 16 + l15][lhi * 8];
#pragma unroll
    for (int ni = 0; ni < 4; ni++)
      bfr[ni] = *(const short8*)&Bl[wn + ni * 16 + l15][lhi * 8];
#pragma unroll
    for (int mi = 0; mi < 4; mi++)
#pragma unroll
      for (int ni = 0; ni < 4; ni++)
        acc[mi][ni] = __builtin_amdgcn_mfma_f32_16x16x32_bf16(
            af[mi], bfr[ni], acc[mi][ni], 0, 0, 0);
    __syncthreads();
  }

#pragma unroll
  for (int mi = 0; mi < 4; mi++)
#pragma unroll
    for (int ni = 0; ni < 4; ni++)
#pragma unroll
      for (int i = 0; i < 4; i++) {
        int row = bm + wm + mi * 16 + lhi * 4 + i;
        int col = bn + wn + ni * 16 + l15;
        float vv = acc[mi][ni][i];
        if (F32OUT)
          ((float*)Cout)[(size_t)row * N + col] = vv;
        else
          ((ushort_t*)Cout)[(size_t)row * N + col] = f2bf(vv);
      }
}

// ---------------- V transpose: Vp[4096][1024] -> Vt[b][h][dd=64][s=1024] ----
__global__ __launch_bounds__(256) void transpose_v_kernel(
    const ushort_t* __restrict__ Vp, ushort_t* __restrict__ Vt) {
  __shared__ ushort_t tile[64][65];
  const int bx = blockIdx.x;  // b*256 + h*16 + c
  const int b = bx >> 8, h = (bx >> 4) & 15, c = bx & 15;
  const int t = threadIdx.x;
#pragma unroll
  for (int i = 0; i < 16; i++) {
    int id = i * 256 + t;
    int tok = id >> 6, dd = id & 63;
    tile[tok][dd] = Vp[(size_t)(b * 1024 + c * 64 + tok) * 1024 + h * 64 + dd];
  }
  __syncthreads();
#pragma unroll
  for (int i = 0; i < 16; i++) {
    int id = i * 256 + t;
    int dd = id >> 6, tok = id & 63;
    Vt[(size_t)((b * 16 + h) * 64 + dd) * 1024 + c * 64 + tok] = tile[tok][dd];
  }
}

// ---------------- flash attention (bf16 MFMA, f32 online softmax) ----------
// grid: 1024 blocks = b(4) x h(16) x qtile(16 of 64 rows). 4 waves, 16 q-rows each.
__global__ __launch_bounds__(256) void attn_kernel(
    const ushort_t* __restrict__ Qp, const ushort_t* __restrict__ Kp,
    const ushort_t* __restrict__ Vt, const int* __restrict__ valid_lens,
    ushort_t* __restrict__ Ob) {
  __shared__ __align__(16) ushort_t Plds[4][16][72];  // per-wave P buffer, padded
  const int tid = threadIdx.x;
  const int w = tid >> 6, lane = tid & 63;
  const int l15 = lane & 15, lhi = lane >> 4;
  const int bx = blockIdx.x;
  const int b = bx >> 8;
  const int h = (bx >> 4) & 15;
  const int qt = bx & 15;
  const int qrow0 = qt * 64 + w * 16;
  const int vlen = valid_lens[b];

  short8 qf0, qf1;
  {
    const ushort_t* qp =
        Qp + (size_t)(b * 1024 + qrow0 + l15) * 1024 + h * 64 + lhi * 8;
    qf0 = *(const short8*)qp;
    qf1 = *(const short8*)(qp + 32);
  }
  float4v zero4 = {0.f, 0.f, 0.f, 0.f};
  float4v o[4] = {zero4, zero4, zero4, zero4};
  float m_i[4] = {NEG_INF, NEG_INF, NEG_INF, NEG_INF};
  float l_i[4] = {0.f, 0.f, 0.f, 0.f};

  const ushort_t* kh = Kp + (size_t)b * 1024 * 1024 + h * 64;
  const ushort_t* vh = Vt + (size_t)(b * 16 + h) * 64 * 1024;

  for (int kt = 0; kt < 16; kt++) {
    const int k0 = kt * 64;
    if (k0 >= vlen) break;  // uniform per block (same b) -> barrier-safe

    // S = Q K^T (16 q-rows x 64 keys), f32 acc
    float4v s[4];
#pragma unroll
    for (int n = 0; n < 4; n++) {
      const ushort_t* kp = kh + (size_t)(k0 + n * 16 + l15) * 1024 + lhi * 8;
      short8 kf0 = *(const short8*)kp;
      short8 kf1 = *(const short8*)(kp + 32);
      s[n] = __builtin_amdgcn_mfma_f32_16x16x32_bf16(qf0, kf0, zero4, 0, 0, 0);
      s[n] = __builtin_amdgcn_mfma_f32_16x16x32_bf16(qf1, kf1, s[n], 0, 0, 0);
    }
    // scale + mask + row max
    float pm[4] = {NEG_INF, NEG_INF, NEG_INF, NEG_INF};
#pragma unroll
    for (int n = 0; n < 4; n++) {
      const bool ok = (k0 + n * 16 + l15) < vlen;
#pragma unroll
      for (int i = 0; i < 4; i++) {
        float v = s[n][i] * 0.125f;
        v = ok ? v : -1e6f;
        s[n][i] = v;
        pm[i] = fmaxf(pm[i], v);
      }
    }
#pragma unroll
    for (int d = 1; d < 16; d <<= 1)
#pragma unroll
      for (int i = 0; i < 4; i++) pm[i] = fmaxf(pm[i], __shfl_xor(pm[i], d, 64));

    float alpha[4], rs[4];
#pragma unroll
    for (int i = 0; i < 4; i++) {
      float mn = fmaxf(m_i[i], pm[i]);
      alpha[i] = __expf(m_i[i] - mn);
      m_i[i] = mn;
      rs[i] = 0.f;
    }
#pragma unroll
    for (int n = 0; n < 4; n++)
#pragma unroll
      for (int i = 0; i < 4; i++) {
        float p = __expf(s[n][i] - m_i[i]);
        s[n][i] = p;
        rs[i] += p;
      }
#pragma unroll
    for (int d = 1; d < 16; d <<= 1)
#pragma unroll
      for (int i = 0; i < 4; i++) rs[i] += __shfl_xor(rs[i], d, 64);
#pragma unroll
    for (int i = 0; i < 4; i++) l_i[i] = l_i[i] * alpha[i] + rs[i];
#pragma unroll
    for (int n = 0; n < 4; n++)
#pragma unroll
      for (int i = 0; i < 4; i++) o[n][i] *= alpha[i];

    // P (C/D layout) -> LDS -> A-frag layout
    __syncthreads();  // protect prev iteration's reads (buffer reuse)
#pragma unroll
    for (int n = 0; n < 4; n++)
#pragma unroll
      for (int i = 0; i < 4; i++)
        Plds[w][lhi * 4 + i][n * 16 + l15] = f2bf(s[n][i]);
    __syncthreads();

    // O += P V  (keys = MFMA K-dim, via Vt so B-frag is contiguous)
#pragma unroll
    for (int c = 0; c < 2; c++) {
      short8 pa = *(const short8*)&Plds[w][l15][c * 32 + lhi * 8];
      const ushort_t* vb = vh + k0 + c * 32 + lhi * 8;
#pragma unroll
      for (int n = 0; n < 4; n++) {
        short8 vf = *(const short8*)(vb + (size_t)(n * 16 + l15) * 1024);
        o[n] = __builtin_amdgcn_mfma_f32_16x16x32_bf16(pa, vf, o[n], 0, 0, 0);
      }
    }
  }

#pragma unroll
  for (int n = 0; n < 4; n++)
#pragma unroll
    for (int i = 0; i < 4; i++) {
      float vout = o[n][i] / l_i[i];
      Ob[(size_t)(b * 1024 + qrow0 + lhi * 4 + i) * 1024 + h * 64 + n * 16 +
         l15] = f2bf(vout);
    }
}

// ---------------- host launch ----------------
extern "C" void kernel_launch(void* const* d_in, const int* in_sizes, int n_in,
                              void* d_out, int out_size, void* d_ws,
                              size_t ws_size, hipStream_t stream) {
  (void)in_sizes;
  (void)n_in;
  (void)out_size;
  (void)ws_size;
  const float* q = (const float*)d_in[0];
  const float* k = (const float*)d_in[1];
  const float* v = (const float*)d_in[2];
  const int* vl = (const int*)d_in[3];
  const float* Wq = (const float*)d_in[4];
  const float* Wk = (const float*)d_in[5];
  const float* Wv = (const float*)d_in[6];
  const float* Wo = (const float*)d_in[7];
  float* out = (float*)d_out;
  char* ws = (char*)d_ws;
  const size_t MB = 1u << 20;

  // layout (40 MB total):
  // [0,8)   tmp: bf16 activation input; later Vt
  // [8,16)  weights bf16 (4 x 2MB)
  // [16,24) Qp   [24,32) Kp   [32,40) Vp, later Ob
  ushort_t* tmp = (ushort_t*)(ws + 0);
  ushort_t* wqb = (ushort_t*)(ws + 8 * MB);
  ushort_t* wkb = (ushort_t*)(ws + 10 * MB);
  ushort_t* wvb = (ushort_t*)(ws + 12 * MB);
  ushort_t* wob = (ushort_t*)(ws + 14 * MB);
  ushort_t* Qp = (ushort_t*)(ws + 16 * MB);
  ushort_t* Kp = (ushort_t*)(ws + 24 * MB);
  ushort_t* Vp = (ushort_t*)(ws + 32 * MB);
  ushort_t* Vtp = tmp;  // reuse after projections
  ushort_t* Ob = Vp;    // reuse after V transposed

  const int NV4_X = (4 * 1024 * 1024) / 4;
  const int NV4_W = (1024 * 1024) / 4;
  dim3 cblk(256);
  cvt_f32_bf16_kernel<<<NV4_W / 256, cblk, 0, stream>>>(Wq, wqb, NV4_W);
  cvt_f32_bf16_kernel<<<NV4_W / 256, cblk, 0, stream>>>(Wk, wkb, NV4_W);
  cvt_f32_bf16_kernel<<<NV4_W / 256, cblk, 0, stream>>>(Wv, wvb, NV4_W);
  cvt_f32_bf16_kernel<<<NV4_W / 256, cblk, 0, stream>>>(Wo, wob, NV4_W);

  dim3 ggrid(8, 32), gblk(256);
  cvt_f32_bf16_kernel<<<NV4_X / 256, cblk, 0, stream>>>(q, tmp, NV4_X);
  gemm_bt128<false><<<ggrid, gblk, 0, stream>>>(tmp, wqb, Qp, 4096, 1024, 1024);
  cvt_f32_bf16_kernel<<<NV4_X / 256, cblk, 0, stream>>>(k, tmp, NV4_X);
  gemm_bt128<false><<<ggrid, gblk, 0, stream>>>(tmp, wkb, Kp, 4096, 1024, 1024);
  cvt_f32_bf16_kernel<<<NV4_X / 256, cblk, 0, stream>>>(v, tmp, NV4_X);
  gemm_bt128<false><<<ggrid, gblk, 0, stream>>>(tmp, wvb, Vp, 4096, 1024, 1024);

  transpose_v_kernel<<<1024, 256, 0, stream>>>(Vp, Vtp);
  attn_kernel<<<1024, 256, 0, stream>>>(Qp, Kp, Vtp, vl, Ob);
  gemm_bt128<true><<<ggrid, gblk, 0, stream>>>(Ob, wob, out, 4096, 1024, 1024);
}

// Round 6
// 241.667 us; speedup vs baseline: 1.1941x; 1.1941x over previous
//
#include <hip/hip_runtime.h>

typedef unsigned short ushort_t;
typedef unsigned int uint32;
typedef __attribute__((ext_vector_type(8))) short short8;
typedef __attribute__((ext_vector_type(4))) float float4v;
typedef __attribute__((ext_vector_type(4))) unsigned short ushort4v;

#define NEG_INF (-__builtin_inff())

__device__ __forceinline__ ushort_t f2bf(float f) {
  uint32 u = __float_as_uint(f);
  u += 0x7fffu + ((u >> 16) & 1u);
  return (ushort_t)(u >> 16);
}

__device__ __forceinline__ void glds16(const void* g, void* l) {
  __builtin_amdgcn_global_load_lds(
      (__attribute__((address_space(1))) const void*)g,
      (__attribute__((address_space(3))) void*)l, 16, 0, 0);
}

// ---------------- batched f32 -> bf16 weight conversion ----------------
struct CvtW {
  const float* in[4];
  ushort_t* out[4];
};

__global__ __launch_bounds__(256) void cvt_w_kernel(CvtW a) {
  const float* in = a.in[blockIdx.y];
  ushort_t* out = a.out[blockIdx.y];
  int i = blockIdx.x * 256 + threadIdx.x;
  float4v v = ((const float4v*)in)[i];
  ushort4v o;
  o.x = f2bf(v.x);
  o.y = f2bf(v.y);
  o.z = f2bf(v.z);
  o.w = f2bf(v.w);
  ((ushort4v*)out)[i] = o;
}

// ---------------- projection GEMM: C_bf16 = cvt(A_f32) * B_bf16^T ----------
// Batched over z=3 (Q,K,V). 128x128 tile, BK=32, 4 waves.
// A (f32) is reg-staged with in-flight f32->bf16 cvt; B via global_load_lds.
struct ProjArgs {
  const float* A[3];
  const ushort_t* B[3];
  ushort_t* C[3];
};

__global__ __launch_bounds__(256) void gemm_proj(ProjArgs pa, int M, int N,
                                                 int K) {
  __shared__ __align__(16) ushort_t Al[128][40];  // padded (80B rows, 16B-mult)
  __shared__ __align__(16) ushort_t Bl[128][32];  // linear (glds dest)
  const int z = blockIdx.z;
  const float* A = pa.A[z];
  const ushort_t* B = pa.B[z];
  ushort_t* C = pa.C[z];
  const int tid = threadIdx.x;
  const int w = tid >> 6, lane = tid & 63;
  const int l15 = lane & 15, lhi = lane >> 4;
  const int bm = blockIdx.y * 128, bn = blockIdx.x * 128;
  const int wm = (w >> 1) * 64, wn = (w & 1) * 64;

  float4v zero4 = {0.f, 0.f, 0.f, 0.f};
  float4v acc[4][4];
  for (int i = 0; i < 4; i++)
    for (int j = 0; j < 4; j++) acc[i][j] = zero4;

  // A staging map: thread covers 2 reps x 8 f32 (two float4s), coalesced.
  const int ar0 = tid >> 2;        // row (rep0), rep1 adds 64
  const int c4 = (2 * tid) & 7;    // even float4-index in row
  // B staging map (glds): row tid>>2, 16B chunk (tid&3)*8 shorts
  const int br = tid >> 2;
  const int bc = (tid & 3) * 8;
  const ushort_t* gb = B + (size_t)(bn + br) * K + bc;
  char* lB = (char*)&Bl[0][0];
  const int wb = w * 1024;

  for (int kt = 0; kt < K; kt += 32) {
    glds16(gb + kt, lB + wb);
    glds16(gb + (size_t)64 * K + kt, lB + 4096 + wb);
#pragma unroll
    for (int rep = 0; rep < 2; rep++) {
      const int row = rep * 64 + ar0;
      const float* p = A + (size_t)(bm + row) * K + kt + c4 * 4;
      float4v u0 = ((const float4v*)p)[0];
      float4v u1 = ((const float4v*)p)[1];
      short8 sv;
      sv[0] = (short)f2bf(u0.x);
      sv[1] = (short)f2bf(u0.y);
      sv[2] = (short)f2bf(u0.z);
      sv[3] = (short)f2bf(u0.w);
      sv[4] = (short)f2bf(u1.x);
      sv[5] = (short)f2bf(u1.y);
      sv[6] = (short)f2bf(u1.z);
      sv[7] = (short)f2bf(u1.w);
      *(short8*)&Al[row][c4 * 4] = sv;
    }
    __syncthreads();
    short8 af[4], bfr[4];
#pragma unroll
    for (int mi = 0; mi < 4; mi++)
      af[mi] = *(const short8*)&Al[wm + mi * 16 + l15][lhi * 8];
#pragma unroll
    for (int ni = 0; ni < 4; ni++)
      bfr[ni] = *(const short8*)&Bl[wn + ni * 16 + l15][lhi * 8];
#pragma unroll
    for (int mi = 0; mi < 4; mi++)
#pragma unroll
      for (int ni = 0; ni < 4; ni++)
        acc[mi][ni] = __builtin_amdgcn_mfma_f32_16x16x32_bf16(
            af[mi], bfr[ni], acc[mi][ni], 0, 0, 0);
    __syncthreads();
  }

#pragma unroll
  for (int mi = 0; mi < 4; mi++)
#pragma unroll
    for (int ni = 0; ni < 4; ni++)
#pragma unroll
      for (int i = 0; i < 4; i++) {
        int row = bm + wm + mi * 16 + lhi * 4 + i;
        int col = bn + wn + ni * 16 + l15;
        C[(size_t)row * N + col] = f2bf(acc[mi][ni][i]);
      }
}

// ---------------- output GEMM: C_f32 = A_bf16 * B_bf16^T -------------------
__global__ __launch_bounds__(256) void gemm_out(const ushort_t* __restrict__ A,
                                                const ushort_t* __restrict__ B,
                                                float* __restrict__ Cout, int M,
                                                int N, int K) {
  __shared__ __align__(16) ushort_t Al[128][32];
  __shared__ __align__(16) ushort_t Bl[128][32];
  const int tid = threadIdx.x;
  const int w = tid >> 6, lane = tid & 63;
  const int l15 = lane & 15, lhi = lane >> 4;
  const int bm = blockIdx.y * 128, bn = blockIdx.x * 128;
  const int wm = (w >> 1) * 64, wn = (w & 1) * 64;

  float4v zero4 = {0.f, 0.f, 0.f, 0.f};
  float4v acc[4][4];
  for (int i = 0; i < 4; i++)
    for (int j = 0; j < 4; j++) acc[i][j] = zero4;

  const int r = tid >> 2;
  const int cc = (tid & 3) * 8;
  const ushort_t* ga = A + (size_t)(bm + r) * K + cc;
  const ushort_t* gb = B + (size_t)(bn + r) * K + cc;
  char* lA = (char*)&Al[0][0];
  char* lB = (char*)&Bl[0][0];
  const int wb = w * 1024;

  for (int kt = 0; kt < K; kt += 32) {
    glds16(ga + kt, lA + wb);
    glds16(ga + (size_t)64 * K + kt, lA + 4096 + wb);
    glds16(gb + kt, lB + wb);
    glds16(gb + (size_t)64 * K + kt, lB + 4096 + wb);
    __syncthreads();
    short8 af[4], bfr[4];
#pragma unroll
    for (int mi = 0; mi < 4; mi++)
      af[mi] = *(const short8*)&Al[wm + mi * 16 + l15][lhi * 8];
#pragma unroll
    for (int ni = 0; ni < 4; ni++)
      bfr[ni] = *(const short8*)&Bl[wn + ni * 16 + l15][lhi * 8];
#pragma unroll
    for (int mi = 0; mi < 4; mi++)
#pragma unroll
      for (int ni = 0; ni < 4; ni++)
        acc[mi][ni] = __builtin_amdgcn_mfma_f32_16x16x32_bf16(
            af[mi], bfr[ni], acc[mi][ni], 0, 0, 0);
    __syncthreads();
  }

#pragma unroll
  for (int mi = 0; mi < 4; mi++)
#pragma unroll
    for (int ni = 0; ni < 4; ni++)
#pragma unroll
      for (int i = 0; i < 4; i++) {
        int row = bm + wm + mi * 16 + lhi * 4 + i;
        int col = bn + wn + ni * 16 + l15;
        Cout[(size_t)row * N + col] = acc[mi][ni][i];
      }
}

// ---------------- V transpose: Vp[4096][1024] -> Vt[b][h][dd=64][s=1024] ----
__global__ __launch_bounds__(256) void transpose_v_kernel(
    const ushort_t* __restrict__ Vp, ushort_t* __restrict__ Vt) {
  __shared__ ushort_t tile[64][65];
  const int bx = blockIdx.x;  // b*256 + h*16 + c
  const int b = bx >> 8, h = (bx >> 4) & 15, c = bx & 15;
  const int t = threadIdx.x;
#pragma unroll
  for (int i = 0; i < 16; i++) {
    int id = i * 256 + t;
    int tok = id >> 6, dd = id & 63;
    tile[tok][dd] = Vp[(size_t)(b * 1024 + c * 64 + tok) * 1024 + h * 64 + dd];
  }
  __syncthreads();
#pragma unroll
  for (int i = 0; i < 16; i++) {
    int id = i * 256 + t;
    int dd = id >> 6, tok = id & 63;
    Vt[(size_t)((b * 16 + h) * 64 + dd) * 1024 + c * 64 + tok] = tile[tok][dd];
  }
}

// ---------------- flash attention: 1-wave blocks, no barriers --------------
// grid 4096 = b(4) x h(16) x qtile(64 of 16 rows). 64 threads.
__global__ __launch_bounds__(64) void attn_kernel(
    const ushort_t* __restrict__ Qp, const ushort_t* __restrict__ Kp,
    const ushort_t* __restrict__ Vt, const int* __restrict__ valid_lens,
    ushort_t* __restrict__ Ob) {
  __shared__ __align__(16) ushort_t Plds[16][72];
  const int lane = threadIdx.x & 63;
  const int l15 = lane & 15, lhi = lane >> 4;
  const int bx = blockIdx.x;
  const int b = bx >> 10;
  const int h = (bx >> 6) & 15;
  const int qt = bx & 63;
  const int qrow0 = qt * 16;
  const int vlen = valid_lens[b];

  short8 qf0, qf1;
  {
    const ushort_t* qp =
        Qp + (size_t)(b * 1024 + qrow0 + l15) * 1024 + h * 64 + lhi * 8;
    qf0 = *(const short8*)qp;
    qf1 = *(const short8*)(qp + 32);
  }
  float4v zero4 = {0.f, 0.f, 0.f, 0.f};
  float4v o[4] = {zero4, zero4, zero4, zero4};
  float m_i[4] = {NEG_INF, NEG_INF, NEG_INF, NEG_INF};
  float l_i[4] = {0.f, 0.f, 0.f, 0.f};

  const ushort_t* kh = Kp + (size_t)b * 1024 * 1024 + h * 64;
  const ushort_t* vh = Vt + (size_t)(b * 16 + h) * 64 * 1024;

  for (int kt = 0; kt < 16; kt++) {
    const int k0 = kt * 64;
    if (k0 >= vlen) break;  // uniform per wave (same b)

    float4v s[4];
#pragma unroll
    for (int n = 0; n < 4; n++) {
      const ushort_t* kp = kh + (size_t)(k0 + n * 16 + l15) * 1024 + lhi * 8;
      short8 kf0 = *(const short8*)kp;
      short8 kf1 = *(const short8*)(kp + 32);
      s[n] = __builtin_amdgcn_mfma_f32_16x16x32_bf16(qf0, kf0, zero4, 0, 0, 0);
      s[n] = __builtin_amdgcn_mfma_f32_16x16x32_bf16(qf1, kf1, s[n], 0, 0, 0);
    }
    float pm[4] = {NEG_INF, NEG_INF, NEG_INF, NEG_INF};
#pragma unroll
    for (int n = 0; n < 4; n++) {
      const bool ok = (k0 + n * 16 + l15) < vlen;
#pragma unroll
      for (int i = 0; i < 4; i++) {
        float v = s[n][i] * 0.125f;
        v = ok ? v : -1e6f;
        s[n][i] = v;
        pm[i] = fmaxf(pm[i], v);
      }
    }
#pragma unroll
    for (int d = 1; d < 16; d <<= 1)
#pragma unroll
      for (int i = 0; i < 4; i++) pm[i] = fmaxf(pm[i], __shfl_xor(pm[i], d, 64));

    float alpha[4], rs[4];
#pragma unroll
    for (int i = 0; i < 4; i++) {
      float mn = fmaxf(m_i[i], pm[i]);
      alpha[i] = __expf(m_i[i] - mn);
      m_i[i] = mn;
      rs[i] = 0.f;
    }
#pragma unroll
    for (int n = 0; n < 4; n++)
#pragma unroll
      for (int i = 0; i < 4; i++) {
        float p = __expf(s[n][i] - m_i[i]);
        s[n][i] = p;
        rs[i] += p;
      }
#pragma unroll
    for (int d = 1; d < 16; d <<= 1)
#pragma unroll
      for (int i = 0; i < 4; i++) rs[i] += __shfl_xor(rs[i], d, 64);
#pragma unroll
    for (int i = 0; i < 4; i++) l_i[i] = l_i[i] * alpha[i] + rs[i];
#pragma unroll
    for (int n = 0; n < 4; n++)
#pragma unroll
      for (int i = 0; i < 4; i++) o[n][i] *= alpha[i];

    // P (C/D layout) -> LDS -> A-frag layout (wave-private; no barrier needed)
#pragma unroll
    for (int n = 0; n < 4; n++)
#pragma unroll
      for (int i = 0; i < 4; i++)
        Plds[lhi * 4 + i][n * 16 + l15] = f2bf(s[n][i]);

#pragma unroll
    for (int c = 0; c < 2; c++) {
      short8 pa = *(const short8*)&Plds[l15][c * 32 + lhi * 8];
      const ushort_t* vb = vh + k0 + c * 32 + lhi * 8;
#pragma unroll
      for (int n = 0; n < 4; n++) {
        short8 vf = *(const short8*)(vb + (size_t)(n * 16 + l15) * 1024);
        o[n] = __builtin_amdgcn_mfma_f32_16x16x32_bf16(pa, vf, o[n], 0, 0, 0);
      }
    }
  }

#pragma unroll
  for (int n = 0; n < 4; n++)
#pragma unroll
    for (int i = 0; i < 4; i++) {
      float vout = o[n][i] / l_i[i];
      Ob[(size_t)(b * 1024 + qrow0 + lhi * 4 + i) * 1024 + h * 64 + n * 16 +
         l15] = f2bf(vout);
    }
}

// ---------------- host launch ----------------
extern "C" void kernel_launch(void* const* d_in, const int* in_sizes, int n_in,
                              void* d_out, int out_size, void* d_ws,
                              size_t ws_size, hipStream_t stream) {
  (void)in_sizes;
  (void)n_in;
  (void)out_size;
  (void)ws_size;
  const float* q = (const float*)d_in[0];
  const float* k = (const float*)d_in[1];
  const float* v = (const float*)d_in[2];
  const int* vl = (const int*)d_in[3];
  const float* Wq = (const float*)d_in[4];
  const float* Wk = (const float*)d_in[5];
  const float* Wv = (const float*)d_in[6];
  const float* Wo = (const float*)d_in[7];
  float* out = (float*)d_out;
  char* ws = (char*)d_ws;
  const size_t MB = 1u << 20;

  // layout (40 MB): weights bf16 [0,8), Qp [8,16), Kp [16,24), Vp [24,32),
  // Vt [32,40), Ob aliases Vp (dead after transpose).
  ushort_t* wqb = (ushort_t*)(ws + 0 * MB);
  ushort_t* wkb = (ushort_t*)(ws + 2 * MB);
  ushort_t* wvb = (ushort_t*)(ws + 4 * MB);
  ushort_t* wob = (ushort_t*)(ws + 6 * MB);
  ushort_t* Qp = (ushort_t*)(ws + 8 * MB);
  ushort_t* Kp = (ushort_t*)(ws + 16 * MB);
  ushort_t* Vp = (ushort_t*)(ws + 24 * MB);
  ushort_t* Vtp = (ushort_t*)(ws + 32 * MB);
  ushort_t* Ob = Vp;

  CvtW cw;
  cw.in[0] = Wq;
  cw.in[1] = Wk;
  cw.in[2] = Wv;
  cw.in[3] = Wo;
  cw.out[0] = wqb;
  cw.out[1] = wkb;
  cw.out[2] = wvb;
  cw.out[3] = wob;
  cvt_w_kernel<<<dim3(1024, 4), 256, 0, stream>>>(cw);

  ProjArgs pa;
  pa.A[0] = q;
  pa.A[1] = k;
  pa.A[2] = v;
  pa.B[0] = wqb;
  pa.B[1] = wkb;
  pa.B[2] = wvb;
  pa.C[0] = Qp;
  pa.C[1] = Kp;
  pa.C[2] = Vp;
  gemm_proj<<<dim3(8, 32, 3), 256, 0, stream>>>(pa, 4096, 1024, 1024);

  transpose_v_kernel<<<1024, 256, 0, stream>>>(Vp, Vtp);
  attn_kernel<<<4096, 64, 0, stream>>>(Qp, Kp, Vtp, vl, Ob);
  gemm_out<<<dim3(8, 32), 256, 0, stream>>>(Ob, wob, out, 4096, 1024, 1024);
}

// Round 7
// 233.787 us; speedup vs baseline: 1.2344x; 1.0337x over previous
//
#include <hip/hip_runtime.h>

typedef unsigned short ushort_t;
typedef unsigned int uint32;
typedef __attribute__((ext_vector_type(8))) short short8;
typedef __attribute__((ext_vector_type(4))) float float4v;
typedef __attribute__((ext_vector_type(4))) unsigned short ushort4v;

#define NEG_INF (-__builtin_inff())

__device__ __forceinline__ ushort_t f2bf(float f) {
  uint32 u = __float_as_uint(f);
  u += 0x7fffu + ((u >> 16) & 1u);
  return (ushort_t)(u >> 16);
}

__device__ __forceinline__ void glds16(const void* g, void* l) {
  __builtin_amdgcn_global_load_lds(
      (__attribute__((address_space(1))) const void*)g,
      (__attribute__((address_space(3))) void*)l, 16, 0, 0);
}

// ---------------- batched f32 -> bf16 weight conversion ----------------
struct CvtW {
  const float* in[4];
  ushort_t* out[4];
};

__global__ __launch_bounds__(256) void cvt_w_kernel(CvtW a) {
  const float* in = a.in[blockIdx.y];
  ushort_t* out = a.out[blockIdx.y];
  int i = blockIdx.x * 256 + threadIdx.x;
  float4v v = ((const float4v*)in)[i];
  ushort4v o;
  o.x = f2bf(v.x);
  o.y = f2bf(v.y);
  o.z = f2bf(v.z);
  o.w = f2bf(v.w);
  ((ushort4v*)out)[i] = o;
}

// ---------------- projection GEMM: C_bf16 = cvt(A_f32) * B_bf16^T ----------
// 128x128 tile, BK=32, 4 waves, batched z=3 via XCD-chunked 1D decode.
// LDS XOR-swizzle (chunk ^= (row>>1)&3): A swizzled at reg-store, B via
// pre-swizzled GLOBAL source feeding linear global_load_lds (rule #21).
struct ProjArgs {
  const float* A[3];
  const ushort_t* B[3];
  ushort_t* C[3];
};

__global__ __launch_bounds__(256) void gemm_proj(ProjArgs pa, int M, int N,
                                                 int K) {
  __shared__ __align__(16) ushort_t Al[128][32];
  __shared__ __align__(16) ushort_t Bl[128][32];
  // XCD-chunked bijective remap: nwg=768=8*96, consecutive swz share A-tile
  // (bn fastest) and land on one XCD -> A fetched once, B L2-resident.
  const int orig = blockIdx.x + (blockIdx.y << 3) + (blockIdx.z << 8);
  const int swz = (orig & 7) * 96 + (orig >> 3);
  const int bn = (swz & 7) * 128;
  const int bm = ((swz >> 3) & 31) * 128;
  const int z = swz >> 8;
  const float* A = pa.A[z];
  const ushort_t* B = pa.B[z];
  ushort_t* C = pa.C[z];
  const int tid = threadIdx.x;
  const int w = tid >> 6, lane = tid & 63;
  const int l15 = lane & 15, lhi = lane >> 4;

  const int wm = (w >> 1) * 64, wn = (w & 1) * 64;

  float4v zero4 = {0.f, 0.f, 0.f, 0.f};
  float4v acc[4][4];
  for (int i = 0; i < 4; i++)
    for (int j = 0; j < 4; j++) acc[i][j] = zero4;

  // staging maps: row = tid>>2 (+64 for 2nd half), 16B chunk = tid&3.
  // swizzle s(row) = (row>>1)&3; s(row) == s(row+64), so one value/thread.
  const int sr = tid >> 2;
  const int sc = tid & 3;
  const int ssw = sc ^ ((sr >> 1) & 3);
  // B: pre-swizzled global source so linear glds lands swizzled.
  const ushort_t* gb = B + (size_t)(bn + sr) * K + ssw * 8;
  char* lB = (char*)&Bl[0][0];
  const int wb = w * 1024;
  // A: f32 source (two float4 = 16B bf16 after cvt), store swizzled.
  const float* gaf = A + (size_t)(bm + sr) * K + sc * 8;

  // read swizzle: (row>>1)&3 with row = base16k + l15 -> (l15>>1)&3
  const int rsw8 = (lhi ^ ((l15 >> 1) & 3)) * 8;

  for (int kt = 0; kt < K; kt += 32) {
    glds16(gb + kt, lB + wb);
    glds16(gb + (size_t)64 * K + kt, lB + 4096 + wb);
#pragma unroll
    for (int rep = 0; rep < 2; rep++) {
      const int row = rep * 64 + sr;
      const float* p = gaf + (size_t)rep * 64 * K + kt;
      float4v u0 = ((const float4v*)p)[0];
      float4v u1 = ((const float4v*)p)[1];
      short8 sv;
      sv[0] = (short)f2bf(u0.x);
      sv[1] = (short)f2bf(u0.y);
      sv[2] = (short)f2bf(u0.z);
      sv[3] = (short)f2bf(u0.w);
      sv[4] = (short)f2bf(u1.x);
      sv[5] = (short)f2bf(u1.y);
      sv[6] = (short)f2bf(u1.z);
      sv[7] = (short)f2bf(u1.w);
      *(short8*)&Al[row][ssw * 8] = sv;
    }
    __syncthreads();
    short8 af[4], bfr[4];
#pragma unroll
    for (int mi = 0; mi < 4; mi++)
      af[mi] = *(const short8*)&Al[wm + mi * 16 + l15][rsw8];
#pragma unroll
    for (int ni = 0; ni < 4; ni++)
      bfr[ni] = *(const short8*)&Bl[wn + ni * 16 + l15][rsw8];
#pragma unroll
    for (int mi = 0; mi < 4; mi++)
#pragma unroll
      for (int ni = 0; ni < 4; ni++)
        acc[mi][ni] = __builtin_amdgcn_mfma_f32_16x16x32_bf16(
            af[mi], bfr[ni], acc[mi][ni], 0, 0, 0);
    __syncthreads();
  }

#pragma unroll
  for (int mi = 0; mi < 4; mi++)
#pragma unroll
    for (int ni = 0; ni < 4; ni++)
#pragma unroll
      for (int i = 0; i < 4; i++) {
        int row = bm + wm + mi * 16 + lhi * 4 + i;
        int col = bn + wn + ni * 16 + l15;
        C[(size_t)row * N + col] = f2bf(acc[mi][ni][i]);
      }
}

// ---------------- output GEMM: C_f32 = A_bf16 * B_bf16^T -------------------
// Same XCD-chunk remap (nwg=256=8*32) + XOR swizzle via pre-swizzled sources.
__global__ __launch_bounds__(256) void gemm_out(const ushort_t* __restrict__ A,
                                                const ushort_t* __restrict__ B,
                                                float* __restrict__ Cout, int M,
                                                int N, int K) {
  __shared__ __align__(16) ushort_t Al[128][32];
  __shared__ __align__(16) ushort_t Bl[128][32];
  const int orig = blockIdx.x + (blockIdx.y << 3);
  const int swz = (orig & 7) * 32 + (orig >> 3);
  const int bn = (swz & 7) * 128;
  const int bm = (swz >> 3) * 128;
  const int tid = threadIdx.x;
  const int w = tid >> 6, lane = tid & 63;
  const int l15 = lane & 15, lhi = lane >> 4;
  const int wm = (w >> 1) * 64, wn = (w & 1) * 64;

  float4v zero4 = {0.f, 0.f, 0.f, 0.f};
  float4v acc[4][4];
  for (int i = 0; i < 4; i++)
    for (int j = 0; j < 4; j++) acc[i][j] = zero4;

  const int sr = tid >> 2;
  const int sc = tid & 3;
  const int ssw = sc ^ ((sr >> 1) & 3);
  const ushort_t* ga = A + (size_t)(bm + sr) * K + ssw * 8;
  const ushort_t* gb = B + (size_t)(bn + sr) * K + ssw * 8;
  char* lA = (char*)&Al[0][0];
  char* lB = (char*)&Bl[0][0];
  const int wb = w * 1024;
  const int rsw8 = (lhi ^ ((l15 >> 1) & 3)) * 8;

  for (int kt = 0; kt < K; kt += 32) {
    glds16(ga + kt, lA + wb);
    glds16(ga + (size_t)64 * K + kt, lA + 4096 + wb);
    glds16(gb + kt, lB + wb);
    glds16(gb + (size_t)64 * K + kt, lB + 4096 + wb);
    __syncthreads();
    short8 af[4], bfr[4];
#pragma unroll
    for (int mi = 0; mi < 4; mi++)
      af[mi] = *(const short8*)&Al[wm + mi * 16 + l15][rsw8];
#pragma unroll
    for (int ni = 0; ni < 4; ni++)
      bfr[ni] = *(const short8*)&Bl[wn + ni * 16 + l15][rsw8];
#pragma unroll
    for (int mi = 0; mi < 4; mi++)
#pragma unroll
      for (int ni = 0; ni < 4; ni++)
        acc[mi][ni] = __builtin_amdgcn_mfma_f32_16x16x32_bf16(
            af[mi], bfr[ni], acc[mi][ni], 0, 0, 0);
    __syncthreads();
  }

#pragma unroll
  for (int mi = 0; mi < 4; mi++)
#pragma unroll
    for (int ni = 0; ni < 4; ni++)
#pragma unroll
      for (int i = 0; i < 4; i++) {
        int row = bm + wm + mi * 16 + lhi * 4 + i;
        int col = bn + wn + ni * 16 + l15;
        Cout[(size_t)row * N + col] = acc[mi][ni][i];
      }
}

// ---------------- V transpose: Vp[4096][1024] -> Vt[b][h][dd=64][s=1024] ----
__global__ __launch_bounds__(256) void transpose_v_kernel(
    const ushort_t* __restrict__ Vp, ushort_t* __restrict__ Vt) {
  __shared__ ushort_t tile[64][65];
  const int bx = blockIdx.x;  // b*256 + h*16 + c
  const int b = bx >> 8, h = (bx >> 4) & 15, c = bx & 15;
  const int t = threadIdx.x;
#pragma unroll
  for (int i = 0; i < 16; i++) {
    int id = i * 256 + t;
    int tok = id >> 6, dd = id & 63;
    tile[tok][dd] = Vp[(size_t)(b * 1024 + c * 64 + tok) * 1024 + h * 64 + dd];
  }
  __syncthreads();
#pragma unroll
  for (int i = 0; i < 16; i++) {
    int id = i * 256 + t;
    int dd = id >> 6, tok = id & 63;
    Vt[(size_t)((b * 16 + h) * 64 + dd) * 1024 + c * 64 + tok] = tile[tok][dd];
  }
}

// ---------------- flash attention: 1-wave blocks, no barriers --------------
// grid 4096 = b(4) x h(16) x qtile(64 of 16 rows). 64 threads.
__global__ __launch_bounds__(64) void attn_kernel(
    const ushort_t* __restrict__ Qp, const ushort_t* __restrict__ Kp,
    const ushort_t* __restrict__ Vt, const int* __restrict__ valid_lens,
    ushort_t* __restrict__ Ob) {
  __shared__ __align__(16) ushort_t Plds[16][72];
  const int lane = threadIdx.x & 63;
  const int l15 = lane & 15, lhi = lane >> 4;
  const int bx = blockIdx.x;
  const int b = bx >> 10;
  const int h = (bx >> 6) & 15;
  const int qt = bx & 63;
  const int qrow0 = qt * 16;
  const int vlen = valid_lens[b];

  short8 qf0, qf1;
  {
    const ushort_t* qp =
        Qp + (size_t)(b * 1024 + qrow0 + l15) * 1024 + h * 64 + lhi * 8;
    qf0 = *(const short8*)qp;
    qf1 = *(const short8*)(qp + 32);
  }
  float4v zero4 = {0.f, 0.f, 0.f, 0.f};
  float4v o[4] = {zero4, zero4, zero4, zero4};
  float m_i[4] = {NEG_INF, NEG_INF, NEG_INF, NEG_INF};
  float l_i[4] = {0.f, 0.f, 0.f, 0.f};

  const ushort_t* kh = Kp + (size_t)b * 1024 * 1024 + h * 64;
  const ushort_t* vh = Vt + (size_t)(b * 16 + h) * 64 * 1024;

  for (int kt = 0; kt < 16; kt++) {
    const int k0 = kt * 64;
    if (k0 >= vlen) break;  // uniform per wave (same b)

    float4v s[4];
#pragma unroll
    for (int n = 0; n < 4; n++) {
      const ushort_t* kp = kh + (size_t)(k0 + n * 16 + l15) * 1024 + lhi * 8;
      short8 kf0 = *(const short8*)kp;
      short8 kf1 = *(const short8*)(kp + 32);
      s[n] = __builtin_amdgcn_mfma_f32_16x16x32_bf16(qf0, kf0, zero4, 0, 0, 0);
      s[n] = __builtin_amdgcn_mfma_f32_16x16x32_bf16(qf1, kf1, s[n], 0, 0, 0);
    }
    float pm[4] = {NEG_INF, NEG_INF, NEG_INF, NEG_INF};
#pragma unroll
    for (int n = 0; n < 4; n++) {
      const bool ok = (k0 + n * 16 + l15) < vlen;
#pragma unroll
      for (int i = 0; i < 4; i++) {
        float v = s[n][i] * 0.125f;
        v = ok ? v : -1e6f;
        s[n][i] = v;
        pm[i] = fmaxf(pm[i], v);
      }
    }
#pragma unroll
    for (int d = 1; d < 16; d <<= 1)
#pragma unroll
      for (int i = 0; i < 4; i++) pm[i] = fmaxf(pm[i], __shfl_xor(pm[i], d, 64));

    float alpha[4], rs[4];
#pragma unroll
    for (int i = 0; i < 4; i++) {
      float mn = fmaxf(m_i[i], pm[i]);
      alpha[i] = __expf(m_i[i] - mn);
      m_i[i] = mn;
      rs[i] = 0.f;
    }
#pragma unroll
    for (int n = 0; n < 4; n++)
#pragma unroll
      for (int i = 0; i < 4; i++) {
        float p = __expf(s[n][i] - m_i[i]);
        s[n][i] = p;
        rs[i] += p;
      }
#pragma unroll
    for (int d = 1; d < 16; d <<= 1)
#pragma unroll
      for (int i = 0; i < 4; i++) rs[i] += __shfl_xor(rs[i], d, 64);
#pragma unroll
    for (int i = 0; i < 4; i++) l_i[i] = l_i[i] * alpha[i] + rs[i];
#pragma unroll
    for (int n = 0; n < 4; n++)
#pragma unroll
      for (int i = 0; i < 4; i++) o[n][i] *= alpha[i];

    // P (C/D layout) -> LDS -> A-frag layout (wave-private; no barrier needed)
#pragma unroll
    for (int n = 0; n < 4; n++)
#pragma unroll
      for (int i = 0; i < 4; i++)
        Plds[lhi * 4 + i][n * 16 + l15] = f2bf(s[n][i]);

#pragma unroll
    for (int c = 0; c < 2; c++) {
      short8 pa = *(const short8*)&Plds[l15][c * 32 + lhi * 8];
      const ushort_t* vb = vh + k0 + c * 32 + lhi * 8;
#pragma unroll
      for (int n = 0; n < 4; n++) {
        short8 vf = *(const short8*)(vb + (size_t)(n * 16 + l15) * 1024);
        o[n] = __builtin_amdgcn_mfma_f32_16x16x32_bf16(pa, vf, o[n], 0, 0, 0);
      }
    }
  }

#pragma unroll
  for (int n = 0; n < 4; n++)
#pragma unroll
    for (int i = 0; i < 4; i++) {
      float vout = o[n][i] / l_i[i];
      Ob[(size_t)(b * 1024 + qrow0 + lhi * 4 + i) * 1024 + h * 64 + n * 16 +
         l15] = f2bf(vout);
    }
}

// ---------------- host launch ----------------
extern "C" void kernel_launch(void* const* d_in, const int* in_sizes, int n_in,
                              void* d_out, int out_size, void* d_ws,
                              size_t ws_size, hipStream_t stream) {
  (void)in_sizes;
  (void)n_in;
  (void)out_size;
  (void)ws_size;
  const float* q = (const float*)d_in[0];
  const float* k = (const float*)d_in[1];
  const float* v = (const float*)d_in[2];
  const int* vl = (const int*)d_in[3];
  const float* Wq = (const float*)d_in[4];
  const float* Wk = (const float*)d_in[5];
  const float* Wv = (const float*)d_in[6];
  const float* Wo = (const float*)d_in[7];
  float* out = (float*)d_out;
  char* ws = (char*)d_ws;
  const size_t MB = 1u << 20;

  // layout (40 MB): weights bf16 [0,8), Qp [8,16), Kp [16,24), Vp [24,32),
  // Vt [32,40), Ob aliases Vp (dead after transpose).
  ushort_t* wqb = (ushort_t*)(ws + 0 * MB);
  ushort_t* wkb = (ushort_t*)(ws + 2 * MB);
  ushort_t* wvb = (ushort_t*)(ws + 4 * MB);
  ushort_t* wob = (ushort_t*)(ws + 6 * MB);
  ushort_t* Qp = (ushort_t*)(ws + 8 * MB);
  ushort_t* Kp = (ushort_t*)(ws + 16 * MB);
  ushort_t* Vp = (ushort_t*)(ws + 24 * MB);
  ushort_t* Vtp = (ushort_t*)(ws + 32 * MB);
  ushort_t* Ob = Vp;

  CvtW cw;
  cw.in[0] = Wq;
  cw.in[1] = Wk;
  cw.in[2] = Wv;
  cw.in[3] = Wo;
  cw.out[0] = wqb;
  cw.out[1] = wkb;
  cw.out[2] = wvb;
  cw.out[3] = wob;
  cvt_w_kernel<<<dim3(1024, 4), 256, 0, stream>>>(cw);

  ProjArgs pa;
  pa.A[0] = q;
  pa.A[1] = k;
  pa.A[2] = v;
  pa.B[0] = wqb;
  pa.B[1] = wkb;
  pa.B[2] = wvb;
  pa.C[0] = Qp;
  pa.C[1] = Kp;
  pa.C[2] = Vp;
  gemm_proj<<<dim3(8, 32, 3), 256, 0, stream>>>(pa, 4096, 1024, 1024);

  transpose_v_kernel<<<1024, 256, 0, stream>>>(Vp, Vtp);
  attn_kernel<<<4096, 64, 0, stream>>>(Qp, Kp, Vtp, vl, Ob);
  gemm_out<<<dim3(8, 32), 256, 0, stream>>>(Ob, wob, out, 4096, 1024, 1024);
}

// Round 9
// 225.039 us; speedup vs baseline: 1.2823x; 1.0389x over previous
//
#include <hip/hip_runtime.h>

typedef unsigned short ushort_t;
typedef unsigned int uint32;
typedef __attribute__((ext_vector_type(8))) short short8;
typedef __attribute__((ext_vector_type(4))) float float4v;
typedef __attribute__((ext_vector_type(4))) unsigned short ushort4v;

#define NEG_INF (-__builtin_inff())

__device__ __forceinline__ ushort_t f2bf(float f) {
  uint32 u = __float_as_uint(f);
  u += 0x7fffu + ((u >> 16) & 1u);
  return (ushort_t)(u >> 16);
}

__device__ __forceinline__ void glds16(const void* g, void* l) {
  __builtin_amdgcn_global_load_lds(
      (__attribute__((address_space(1))) const void*)g,
      (__attribute__((address_space(3))) void*)l, 16, 0, 0);
}

// ---------------- batched f32 -> bf16 weight conversion ----------------
struct CvtW {
  const float* in[4];
  ushort_t* out[4];
};

__global__ __launch_bounds__(256) void cvt_w_kernel(CvtW a) {
  const float* in = a.in[blockIdx.y];
  ushort_t* out = a.out[blockIdx.y];
  int i = blockIdx.x * 256 + threadIdx.x;
  float4v v = ((const float4v*)in)[i];
  ushort4v o;
  o.x = f2bf(v.x);
  o.y = f2bf(v.y);
  o.z = f2bf(v.z);
  o.w = f2bf(v.w);
  ((ushort4v*)out)[i] = o;
}

// ---------------- projection GEMM: C_bf16 = cvt(A_f32) * B_bf16^T ----------
// 128x128 tile, BK=32, 4 waves, z=3 batched, XCD-chunked remap, XOR-swizzled
// LDS, and 2-phase double-buffer: tile t+1 staged (glds B + A f32 reg loads)
// BEFORE tile t's MFMA so HBM latency hides under compute. One barrier/iter.
struct ProjArgs {
  const float* A[3];
  const ushort_t* B[3];
  ushort_t* C[3];
};

__global__ __launch_bounds__(256) void gemm_proj(ProjArgs pa, int M, int N,
                                                 int K) {
  __shared__ __align__(16) ushort_t Al[2][128][32];
  __shared__ __align__(16) ushort_t Bl[2][128][32];
  const int orig = blockIdx.x + (blockIdx.y << 3) + (blockIdx.z << 8);
  const int swz = (orig & 7) * 96 + (orig >> 3);
  const int bn = (swz & 7) * 128;
  const int bm = ((swz >> 3) & 31) * 128;
  const int z = swz >> 8;
  const float* A = pa.A[z];
  const ushort_t* B = pa.B[z];
  ushort_t* C = pa.C[z];
  const int tid = threadIdx.x;
  const int w = tid >> 6, lane = tid & 63;
  const int l15 = lane & 15, lhi = lane >> 4;
  const int wm = (w >> 1) * 64, wn = (w & 1) * 64;

  float4v zero4 = {0.f, 0.f, 0.f, 0.f};
  float4v acc[4][4];
  for (int i = 0; i < 4; i++)
    for (int j = 0; j < 4; j++) acc[i][j] = zero4;

  const int sr = tid >> 2;
  const int sc = tid & 3;
  const int ssw = sc ^ ((sr >> 1) & 3);
  const ushort_t* gb = B + (size_t)(bn + sr) * K + ssw * 8;
  char* lBb = (char*)&Bl[0][0][0];
  const int wb = w * 1024;
  const float* gaf = A + (size_t)(bm + sr) * K + sc * 8;
  const int rsw8 = (lhi ^ ((l15 >> 1) & 3)) * 8;
  const int NT = K / 32;

  // prologue: stage tile 0 into buffer 0
  glds16(gb, lBb + wb);
  glds16(gb + (size_t)64 * K, lBb + 4096 + wb);
#pragma unroll
  for (int rep = 0; rep < 2; rep++) {
    const float* p = gaf + (size_t)rep * 64 * K;
    float4v u0 = ((const float4v*)p)[0];
    float4v u1 = ((const float4v*)p)[1];
    short8 sv;
    sv[0] = (short)f2bf(u0.x);
    sv[1] = (short)f2bf(u0.y);
    sv[2] = (short)f2bf(u0.z);
    sv[3] = (short)f2bf(u0.w);
    sv[4] = (short)f2bf(u1.x);
    sv[5] = (short)f2bf(u1.y);
    sv[6] = (short)f2bf(u1.z);
    sv[7] = (short)f2bf(u1.w);
    *(short8*)&Al[0][rep * 64 + sr][ssw * 8] = sv;
  }
  __syncthreads();

  int cur = 0;
  for (int t = 0; t < NT; ++t) {
    const int ktn = (t + 1) * 32;
    const bool pf = (t + 1 < NT);
    float4v pu0[2], pu1[2];
    if (pf) {
      char* lBn = lBb + (cur ^ 1) * 8192;
      glds16(gb + ktn, lBn + wb);
      glds16(gb + (size_t)64 * K + ktn, lBn + 4096 + wb);
#pragma unroll
      for (int rep = 0; rep < 2; rep++) {
        const float* p = gaf + (size_t)rep * 64 * K + ktn;
        pu0[rep] = ((const float4v*)p)[0];
        pu1[rep] = ((const float4v*)p)[1];
      }
    }
    short8 af[4], bfr[4];
#pragma unroll
    for (int mi = 0; mi < 4; mi++)
      af[mi] = *(const short8*)&Al[cur][wm + mi * 16 + l15][rsw8];
#pragma unroll
    for (int ni = 0; ni < 4; ni++)
      bfr[ni] = *(const short8*)&Bl[cur][wn + ni * 16 + l15][rsw8];
#pragma unroll
    for (int mi = 0; mi < 4; mi++)
#pragma unroll
      for (int ni = 0; ni < 4; ni++)
        acc[mi][ni] = __builtin_amdgcn_mfma_f32_16x16x32_bf16(
            af[mi], bfr[ni], acc[mi][ni], 0, 0, 0);
    if (pf) {
#pragma unroll
      for (int rep = 0; rep < 2; rep++) {
        short8 sv;
        sv[0] = (short)f2bf(pu0[rep].x);
        sv[1] = (short)f2bf(pu0[rep].y);
        sv[2] = (short)f2bf(pu0[rep].z);
        sv[3] = (short)f2bf(pu0[rep].w);
        sv[4] = (short)f2bf(pu1[rep].x);
        sv[5] = (short)f2bf(pu1[rep].y);
        sv[6] = (short)f2bf(pu1[rep].z);
        sv[7] = (short)f2bf(pu1[rep].w);
        *(short8*)&Al[cur ^ 1][rep * 64 + sr][ssw * 8] = sv;
      }
    }
    __syncthreads();
    cur ^= 1;
  }

#pragma unroll
  for (int mi = 0; mi < 4; mi++)
#pragma unroll
    for (int ni = 0; ni < 4; ni++)
#pragma unroll
      for (int i = 0; i < 4; i++) {
        int row = bm + wm + mi * 16 + lhi * 4 + i;
        int col = bn + wn + ni * 16 + l15;
        C[(size_t)row * N + col] = f2bf(acc[mi][ni][i]);
      }
}

// ---------------- output GEMM: C_f32 = A_bf16 * B_bf16^T -------------------
// Same remap + swizzle + 2-phase double-buffer (all-glds staging).
__global__ __launch_bounds__(256) void gemm_out(const ushort_t* __restrict__ A,
                                                const ushort_t* __restrict__ B,
                                                float* __restrict__ Cout, int M,
                                                int N, int K) {
  __shared__ __align__(16) ushort_t Al[2][128][32];
  __shared__ __align__(16) ushort_t Bl[2][128][32];
  const int orig = blockIdx.x + (blockIdx.y << 3);
  const int swz = (orig & 7) * 32 + (orig >> 3);
  const int bn = (swz & 7) * 128;
  const int bm = (swz >> 3) * 128;
  const int tid = threadIdx.x;
  const int w = tid >> 6, lane = tid & 63;
  const int l15 = lane & 15, lhi = lane >> 4;
  const int wm = (w >> 1) * 64, wn = (w & 1) * 64;

  float4v zero4 = {0.f, 0.f, 0.f, 0.f};
  float4v acc[4][4];
  for (int i = 0; i < 4; i++)
    for (int j = 0; j < 4; j++) acc[i][j] = zero4;

  const int sr = tid >> 2;
  const int sc = tid & 3;
  const int ssw = sc ^ ((sr >> 1) & 3);
  const ushort_t* ga = A + (size_t)(bm + sr) * K + ssw * 8;
  const ushort_t* gb = B + (size_t)(bn + sr) * K + ssw * 8;
  char* lAb = (char*)&Al[0][0][0];
  char* lBb = (char*)&Bl[0][0][0];
  const int wb = w * 1024;
  const int rsw8 = (lhi ^ ((l15 >> 1) & 3)) * 8;
  const int NT = K / 32;

  glds16(ga, lAb + wb);
  glds16(ga + (size_t)64 * K, lAb + 4096 + wb);
  glds16(gb, lBb + wb);
  glds16(gb + (size_t)64 * K, lBb + 4096 + wb);
  __syncthreads();

  int cur = 0;
  for (int t = 0; t < NT; ++t) {
    const int ktn = (t + 1) * 32;
    if (t + 1 < NT) {
      char* lAn = lAb + (cur ^ 1) * 8192;
      char* lBn = lBb + (cur ^ 1) * 8192;
      glds16(ga + ktn, lAn + wb);
      glds16(ga + (size_t)64 * K + ktn, lAn + 4096 + wb);
      glds16(gb + ktn, lBn + wb);
      glds16(gb + (size_t)64 * K + ktn, lBn + 4096 + wb);
    }
    short8 af[4], bfr[4];
#pragma unroll
    for (int mi = 0; mi < 4; mi++)
      af[mi] = *(const short8*)&Al[cur][wm + mi * 16 + l15][rsw8];
#pragma unroll
    for (int ni = 0; ni < 4; ni++)
      bfr[ni] = *(const short8*)&Bl[cur][wn + ni * 16 + l15][rsw8];
#pragma unroll
    for (int mi = 0; mi < 4; mi++)
#pragma unroll
      for (int ni = 0; ni < 4; ni++)
        acc[mi][ni] = __builtin_amdgcn_mfma_f32_16x16x32_bf16(
            af[mi], bfr[ni], acc[mi][ni], 0, 0, 0);
    __syncthreads();
    cur ^= 1;
  }

#pragma unroll
  for (int mi = 0; mi < 4; mi++)
#pragma unroll
    for (int ni = 0; ni < 4; ni++)
#pragma unroll
      for (int i = 0; i < 4; i++) {
        int row = bm + wm + mi * 16 + lhi * 4 + i;
        int col = bn + wn + ni * 16 + l15;
        Cout[(size_t)row * N + col] = acc[mi][ni][i];
      }
}

// ---------------- V transpose: Vp[4096][1024] -> Vt[b][h][dd=64][s=1024] ----
__global__ __launch_bounds__(256) void transpose_v_kernel(
    const ushort_t* __restrict__ Vp, ushort_t* __restrict__ Vt) {
  __shared__ ushort_t tile[64][65];
  const int bx = blockIdx.x;  // b*256 + h*16 + c
  const int b = bx >> 8, h = (bx >> 4) & 15, c = bx & 15;
  const int t = threadIdx.x;
#pragma unroll
  for (int i = 0; i < 16; i++) {
    int id = i * 256 + t;
    int tok = id >> 6, dd = id & 63;
    tile[tok][dd] = Vp[(size_t)(b * 1024 + c * 64 + tok) * 1024 + h * 64 + dd];
  }
  __syncthreads();
#pragma unroll
  for (int i = 0; i < 16; i++) {
    int id = i * 256 + t;
    int dd = id >> 6, tok = id & 63;
    Vt[(size_t)((b * 16 + h) * 64 + dd) * 1024 + c * 64 + tok] = tile[tok][dd];
  }
}

// ---------------- flash attention: 1-wave blocks, no barriers --------------
// grid 4096 = b(4) x h(16) x qtile(64 of 16 rows). 64 threads.
__global__ __launch_bounds__(64) void attn_kernel(
    const ushort_t* __restrict__ Qp, const ushort_t* __restrict__ Kp,
    const ushort_t* __restrict__ Vt, const int* __restrict__ valid_lens,
    ushort_t* __restrict__ Ob) {
  __shared__ __align__(16) ushort_t Plds[16][72];
  const int lane = threadIdx.x & 63;
  const int l15 = lane & 15, lhi = lane >> 4;
  const int bx = blockIdx.x;
  const int b = bx >> 10;
  const int h = (bx >> 6) & 15;
  const int qt = bx & 63;
  const int qrow0 = qt * 16;
  const int vlen = valid_lens[b];

  short8 qf0, qf1;
  {
    const ushort_t* qp =
        Qp + (size_t)(b * 1024 + qrow0 + l15) * 1024 + h * 64 + lhi * 8;
    qf0 = *(const short8*)qp;
    qf1 = *(const short8*)(qp + 32);
  }
  float4v zero4 = {0.f, 0.f, 0.f, 0.f};
  float4v o[4] = {zero4, zero4, zero4, zero4};
  float m_i[4] = {NEG_INF, NEG_INF, NEG_INF, NEG_INF};
  float l_i[4] = {0.f, 0.f, 0.f, 0.f};

  const ushort_t* kh = Kp + (size_t)b * 1024 * 1024 + h * 64;
  const ushort_t* vh = Vt + (size_t)(b * 16 + h) * 64 * 1024;

  for (int kt = 0; kt < 16; kt++) {
    const int k0 = kt * 64;
    if (k0 >= vlen) break;  // uniform per wave (same b)

    float4v s[4];
#pragma unroll
    for (int n = 0; n < 4; n++) {
      const ushort_t* kp = kh + (size_t)(k0 + n * 16 + l15) * 1024 + lhi * 8;
      short8 kf0 = *(const short8*)kp;
      short8 kf1 = *(const short8*)(kp + 32);
      s[n] = __builtin_amdgcn_mfma_f32_16x16x32_bf16(qf0, kf0, zero4, 0, 0, 0);
      s[n] = __builtin_amdgcn_mfma_f32_16x16x32_bf16(qf1, kf1, s[n], 0, 0, 0);
    }
    float pm[4] = {NEG_INF, NEG_INF, NEG_INF, NEG_INF};
#pragma unroll
    for (int n = 0; n < 4; n++) {
      const bool ok = (k0 + n * 16 + l15) < vlen;
#pragma unroll
      for (int i = 0; i < 4; i++) {
        float v = s[n][i] * 0.125f;
        v = ok ? v : -1e6f;
        s[n][i] = v;
        pm[i] = fmaxf(pm[i], v);
      }
    }
#pragma unroll
    for (int d = 1; d < 16; d <<= 1)
#pragma unroll
      for (int i = 0; i < 4; i++) pm[i] = fmaxf(pm[i], __shfl_xor(pm[i], d, 64));

    float alpha[4], rs[4];
#pragma unroll
    for (int i = 0; i < 4; i++) {
      float mn = fmaxf(m_i[i], pm[i]);
      alpha[i] = __expf(m_i[i] - mn);
      m_i[i] = mn;
      rs[i] = 0.f;
    }
#pragma unroll
    for (int n = 0; n < 4; n++)
#pragma unroll
      for (int i = 0; i < 4; i++) {
        float p = __expf(s[n][i] - m_i[i]);
        s[n][i] = p;
        rs[i] += p;
      }
#pragma unroll
    for (int d = 1; d < 16; d <<= 1)
#pragma unroll
      for (int i = 0; i < 4; i++) rs[i] += __shfl_xor(rs[i], d, 64);
#pragma unroll
    for (int i = 0; i < 4; i++) l_i[i] = l_i[i] * alpha[i] + rs[i];
#pragma unroll
    for (int n = 0; n < 4; n++)
#pragma unroll
      for (int i = 0; i < 4; i++) o[n][i] *= alpha[i];

    // P (C/D layout) -> LDS -> A-frag layout (wave-private; no barrier needed)
#pragma unroll
    for (int n = 0; n < 4; n++)
#pragma unroll
      for (int i = 0; i < 4; i++)
        Plds[lhi * 4 + i][n * 16 + l15] = f2bf(s[n][i]);

#pragma unroll
    for (int c = 0; c < 2; c++) {
      short8 pa = *(const short8*)&Plds[l15][c * 32 + lhi * 8];
      const ushort_t* vb = vh + k0 + c * 32 + lhi * 8;
#pragma unroll
      for (int n = 0; n < 4; n++) {
        short8 vf = *(const short8*)(vb + (size_t)(n * 16 + l15) * 1024);
        o[n] = __builtin_amdgcn_mfma_f32_16x16x32_bf16(pa, vf, o[n], 0, 0, 0);
      }
    }
  }

#pragma unroll
  for (int n = 0; n < 4; n++)
#pragma unroll
    for (int i = 0; i < 4; i++) {
      float vout = o[n][i] / l_i[i];
      Ob[(size_t)(b * 1024 + qrow0 + lhi * 4 + i) * 1024 + h * 64 + n * 16 +
         l15] = f2bf(vout);
    }
}

// ---------------- host launch ----------------
extern "C" void kernel_launch(void* const* d_in, const int* in_sizes, int n_in,
                              void* d_out, int out_size, void* d_ws,
                              size_t ws_size, hipStream_t stream) {
  (void)in_sizes;
  (void)n_in;
  (void)out_size;
  (void)ws_size;
  const float* q = (const float*)d_in[0];
  const float* k = (const float*)d_in[1];
  const float* v = (const float*)d_in[2];
  const int* vl = (const int*)d_in[3];
  const float* Wq = (const float*)d_in[4];
  const float* Wk = (const float*)d_in[5];
  const float* Wv = (const float*)d_in[6];
  const float* Wo = (const float*)d_in[7];
  float* out = (float*)d_out;
  char* ws = (char*)d_ws;
  const size_t MB = 1u << 20;

  // layout (40 MB): weights bf16 [0,8), Qp [8,16), Kp [16,24), Vp [24,32),
  // Vt [32,40), Ob aliases Vp (dead after transpose).
  ushort_t* wqb = (ushort_t*)(ws + 0 * MB);
  ushort_t* wkb = (ushort_t*)(ws + 2 * MB);
  ushort_t* wvb = (ushort_t*)(ws + 4 * MB);
  ushort_t* wob = (ushort_t*)(ws + 6 * MB);
  ushort_t* Qp = (ushort_t*)(ws + 8 * MB);
  ushort_t* Kp = (ushort_t*)(ws + 16 * MB);
  ushort_t* Vp = (ushort_t*)(ws + 24 * MB);
  ushort_t* Vtp = (ushort_t*)(ws + 32 * MB);
  ushort_t* Ob = Vp;

  CvtW cw;
  cw.in[0] = Wq;
  cw.in[1] = Wk;
  cw.in[2] = Wv;
  cw.in[3] = Wo;
  cw.out[0] = wqb;
  cw.out[1] = wkb;
  cw.out[2] = wvb;
  cw.out[3] = wob;
  cvt_w_kernel<<<dim3(1024, 4), 256, 0, stream>>>(cw);

  ProjArgs pa;
  pa.A[0] = q;
  pa.A[1] = k;
  pa.A[2] = v;
  pa.B[0] = wqb;
  pa.B[1] = wkb;
  pa.B[2] = wvb;
  pa.C[0] = Qp;
  pa.C[1] = Kp;
  pa.C[2] = Vp;
  gemm_proj<<<dim3(8, 32, 3), 256, 0, stream>>>(pa, 4096, 1024, 1024);

  transpose_v_kernel<<<1024, 256, 0, stream>>>(Vp, Vtp);
  attn_kernel<<<4096, 64, 0, stream>>>(Qp, Kp, Vtp, vl, Ob);
  gemm_out<<<dim3(8, 32), 256, 0, stream>>>(Ob, wob, out, 4096, 1024, 1024);
}